// Round 13
// baseline (217.149 us; speedup 1.0000x reference)
//
#include <hip/hip_runtime.h>
#include <hip/hip_bf16.h>

// Problem: N=4096, Dx=512, Dz=64.
// out[0]=total, out[1]=rank_loss, out[2]=pairdist_loss (f32).
//
// Pipeline:
//   1. prep: nx[i]=sum x[i]^2 (f32), nz likewise; cast x,z to bf16.
//   2. gram_both (ONE dispatch, 2080 triangular 64x64-tile blocks): each
//      block runs the tile pipeline twice — z (K=64) then x (K=512).
//      Small tiles = 8x more blocks than r12's 128-tiles: 5+ blocks/CU
//      co-resident so one block's vmcnt-drain overlaps another's MFMA
//      (r12 diagnosis: ~2500 cyc/K-iter, ~2000 of it barrier-drain stall,
//      with only 2.06 blocks/CU to hide it). bf16 MFMA, dbuf staging,
//      LDS-staged coalesced uint4 dist writes, mirror via LDS transpose.
//      q0=min(floor(d*qscale),65535), qscale 1024 (x) / 2048 (z).
//   3. rank kernel: 1024 blocks x 256 thr, 4 rows/block, register
//      prefetch; global-normalized 11-bit bins; ds_add_rtn count+offset
//      pass; dual scan; plain ds_read final pass; |rx-rz| inline.
//   4. finalize: 3 scalars.

#define N 4096
#define DX 512
#define DZ 64
#define NBIN 2048
#define NWRD (NBIN / 2)
#define RPB 4

typedef __attribute__((ext_vector_type(8))) short short8;
typedef __attribute__((ext_vector_type(4))) float float4v;

// stats word layout (u32 index into qstats base):
//   [0..1] rank_acc (u64)  [2..3] pd_acc (double)
//   [4] maxx [5] maxz      [6] minx [7] minz
#define ST_MAX 4
#define ST_MIN 6

// ---------------- async 16B global -> LDS ----------------
__device__ __forceinline__ void async16(const void* g, void* l) {
  __builtin_amdgcn_global_load_lds(
      (const __attribute__((address_space(1))) unsigned int*)(g),
      (__attribute__((address_space(3))) unsigned int*)(l), 16, 0, 0);
}

// ---------------- prep: norms + bf16 casts ----------------
__global__ __launch_bounds__(256) void prep_kernel(
    const float* __restrict__ x, const float* __restrict__ z,
    __hip_bfloat16* __restrict__ xb, __hip_bfloat16* __restrict__ zb,
    float* __restrict__ nx, float* __restrict__ nz) {
  int row = blockIdx.x;
  int tid = threadIdx.x;
  __shared__ float red[256];

  float sx = 0.f;
  for (int c = tid; c < DX; c += 256) {
    float v = x[(size_t)row * DX + c];
    xb[(size_t)row * DX + c] = __float2bfloat16(v);
    sx += v * v;
  }
  red[tid] = sx;
  __syncthreads();
  for (int s = 128; s > 0; s >>= 1) {
    if (tid < s) red[tid] += red[tid + s];
    __syncthreads();
  }
  if (tid == 0) nx[row] = red[0];
  __syncthreads();

  float sz = 0.f;
  if (tid < DZ) {
    float v = z[(size_t)row * DZ + tid];
    zb[(size_t)row * DZ + tid] = __float2bfloat16(v);
    sz = v * v;
  }
  red[tid] = sz;
  __syncthreads();
  for (int s = 128; s > 0; s >>= 1) {
    if (tid < s) red[tid] += red[tid + s];
    __syncthreads();
  }
  if (tid == 0) nz[row] = red[0];
}

// ------- bf16 MFMA Gram, 64x64 tiles, symmetric compact grid -------------
#define TILE 64
#define BK 32
#define PADW 68   // ctile row stride in u16 (multiple of 4 -> 8B-aligned b64)
#define NT 64     // tiles per dimension
#define NTRI 2080 // NT*(NT+1)/2

__device__ __forceinline__ void gram_tile(
    const __hip_bfloat16* __restrict__ Abf, const float* __restrict__ norms,
    unsigned short* __restrict__ distq, int K, float qscale,
    unsigned* __restrict__ qstats, int slot, int by, int bx, char* smem,
    unsigned* mmx) {
  unsigned short* ctile = (unsigned short*)smem;  // 64*68*2 = 8704 B, aliased

  int tid = threadIdx.x;
  int wave = tid >> 6, lane = tid & 63;
  int wr = wave >> 1, wc = wave & 1;          // 2x2 wave grid, 32x32 each
  int quad = lane >> 4, l15 = lane & 15;

  int rowBase = by * TILE;
  int colBase = bx * TILE;

  float4v acc[2][2];
#pragma unroll
  for (int mi = 0; mi < 2; ++mi)
#pragma unroll
    for (int ni = 0; ni < 2; ++ni) {
      float4v zv = {0.f, 0.f, 0.f, 0.f};
      acc[mi][ni] = zv;
    }

  const char* Ab = (const char*)Abf;
  const size_t rb = (size_t)K * 2;  // row bytes
  int rl = tid >> 2;         // staging row (0..63), 4 threads/row
  int cl = (tid & 3) * 16;   // byte col within 64B row

  // stage K-chunk kc into buffer b: A tile 64x32 (4 KB) + B tile (4 KB)
  auto stage = [&](int kc, int b) {
    const char* base = Ab + (size_t)kc * 2 + cl;
    char* sA = smem + b * 8192;
    char* sB = smem + b * 8192 + 4096;
    async16(base + (size_t)(rowBase + rl) * rb, sA + rl * 64 + cl);
    async16(base + (size_t)(colBase + rl) * rb, sB + rl * 64 + cl);
  };

  stage(0, 0);
  int ib = 0;
  for (int kc = 0; kc < K; kc += BK, ib ^= 1) {
    __syncthreads();  // drains staging of current buf
    if (kc + BK < K) stage(kc + BK, ib ^ 1);  // in flight during MFMA

    const short* As = (const short*)(smem + ib * 8192);
    const short* Bs = (const short*)(smem + ib * 8192 + 4096);
    short8 a[2], b[2];
#pragma unroll
    for (int mi = 0; mi < 2; ++mi)
      a[mi] = *(const short8*)(&As[(wr * 32 + mi * 16 + l15) * BK + quad * 8]);
#pragma unroll
    for (int ni = 0; ni < 2; ++ni)
      b[ni] = *(const short8*)(&Bs[(wc * 32 + ni * 16 + l15) * BK + quad * 8]);
#pragma unroll
    for (int mi = 0; mi < 2; ++mi)
#pragma unroll
      for (int ni = 0; ni < 2; ++ni)
        acc[mi][ni] = __builtin_amdgcn_mfma_f32_16x16x32_bf16(
            a[mi], b[ni], acc[mi][ni], 0, 0, 0);
  }
  __syncthreads();  // staging reads done before ctile aliasing write

  // ---- quantize: stage [row][col] in LDS + keep packed u64 per column ----
  unsigned mn = 0xFFFFu, mx = 0u;
  unsigned long long qp[2][2];
#pragma unroll
  for (int mi = 0; mi < 2; ++mi) {
#pragma unroll
    for (int ni = 0; ni < 2; ++ni) {
      int colL = wc * 32 + ni * 16 + l15;
      float ncol = norms[colBase + colL];
      unsigned long long pk = 0ull;
#pragma unroll
      for (int r = 0; r < 4; ++r) {
        int rowL = wr * 32 + mi * 16 + quad * 4 + r;
        int row = rowBase + rowL;
        float sq = norms[row] + ncol - 2.0f * acc[mi][ni][r];
        float d = sq > 0.f ? sqrtf(sq) : 0.f;
        if (row == colBase + colL) d = 0.f;
        unsigned q = (unsigned)(d * qscale);
        q = q > 65535u ? 65535u : q;
        ctile[rowL * PADW + colL] = (unsigned short)q;
        pk |= (unsigned long long)q << (16 * r);
        mx = max(mx, q);
        mn = min(mn, (row == colBase + colL) ? 0xFFFFu : q);
      }
      qp[mi][ni] = pk;
    }
  }
  __syncthreads();

  // ---- pass A: upper tile, coalesced uint4 rows (64 rows x 8 uint4) ----
  {
    const unsigned* cw = (const unsigned*)ctile;  // row stride 34 words
#pragma unroll
    for (int s = 0; s < 2; ++s) {
      int g = s * 256 + tid;
      int i = g >> 3, ch = g & 7;
      int wb = i * (PADW / 2) + ch * 4;
      uint4 v;
      v.x = cw[wb + 0];
      v.y = cw[wb + 1];
      v.z = cw[wb + 2];
      v.w = cw[wb + 3];
      *(uint4*)(distq + (size_t)(rowBase + i) * N + colBase + ch * 8) = v;
    }
  }

  // ---- pass B: mirror tile via transposed restage (off-diag only) ----
  if (by != bx) {
    __syncthreads();  // pass-A reads done before overwrite
#pragma unroll
    for (int mi = 0; mi < 2; ++mi)
#pragma unroll
      for (int ni = 0; ni < 2; ++ni) {
        int colL = wc * 32 + ni * 16 + l15;
        int rowL0 = wr * 32 + mi * 16 + quad * 4;
        *(unsigned long long*)&ctile[colL * PADW + rowL0] = qp[mi][ni];
      }
    __syncthreads();
    const unsigned* cw = (const unsigned*)ctile;
#pragma unroll
    for (int s = 0; s < 2; ++s) {
      int g = s * 256 + tid;
      int j = g >> 3, ch = g & 7;
      int wb = j * (PADW / 2) + ch * 4;
      uint4 v;
      v.x = cw[wb + 0];
      v.y = cw[wb + 1];
      v.z = cw[wb + 2];
      v.w = cw[wb + 3];
      *(uint4*)(distq + (size_t)(colBase + j) * N + rowBase + ch * 8) = v;
    }
  }

  // ---- block-level min/max reduce -> 2 device atomics per tile ----
#pragma unroll
  for (int d = 32; d; d >>= 1) {
    mn = min(mn, (unsigned)__shfl_xor((int)mn, d, 64));
    mx = max(mx, (unsigned)__shfl_xor((int)mx, d, 64));
  }
  __syncthreads();  // LDS reads done; mmx reuse safe
  if (lane == 0) {
    mmx[wave] = mn;
    mmx[4 + wave] = mx;
  }
  __syncthreads();
  if (tid == 0) {
    unsigned bmn = min(min(mmx[0], mmx[1]), min(mmx[2], mmx[3]));
    unsigned bmx = max(max(mmx[4], mmx[5]), max(mmx[6], mmx[7]));
    atomicMin(&qstats[ST_MIN + slot], bmn);
    atomicMax(&qstats[ST_MAX + slot], bmx);
  }
}

__global__ __launch_bounds__(256, 5) void gram_both_kernel(
    const __hip_bfloat16* __restrict__ xb, const __hip_bfloat16* __restrict__ zb,
    const float* __restrict__ nx, const float* __restrict__ nz,
    unsigned short* __restrict__ qx16, unsigned short* __restrict__ qz16,
    unsigned* __restrict__ qstats) {
  __shared__ alignas(16) char smem[16384];  // dbuf staging; ctile aliased
  __shared__ unsigned mmx[8];

  // compact upper-triangular decode, NT=64: row by has 64-by tiles
  int idx = (int)blockIdx.x;
  int by = (int)((129.0f - sqrtf(16641.0f - 8.0f * (float)idx)) * 0.5f);
  while (((by + 1) * (129 - (by + 1))) / 2 <= idx) ++by;
  while ((by * (129 - by)) / 2 > idx) --by;
  int bx = by + (idx - (by * (129 - by)) / 2);

  // z tile first (cheap, K=64), then x tile (K=512)
  gram_tile(zb, nz, qz16, DZ, 2048.0f, qstats, 1, by, bx, smem, mmx);
  __syncthreads();
  gram_tile(xb, nx, qx16, DX, 1024.0f, qstats, 0, by, bx, smem, mmx);
}

// ---------------- counting-based per-row ranks (4 rows / block) ----------
__device__ __forceinline__ int hsw(int w) { return w ^ ((w >> 5) & 31); }

__global__ __launch_bounds__(256) void rank_kernel(
    const unsigned short* __restrict__ qx,
    const unsigned short* __restrict__ qz,
    const unsigned* __restrict__ qstats,
    unsigned long long* __restrict__ rank_acc, double* __restrict__ pd_acc) {
  __shared__ unsigned histX[NWRD];  // 4 KB
  __shared__ unsigned histZ[NWRD];  // 4 KB
  __shared__ unsigned xch[32];

  int t = threadIdx.x, lane = t & 63, wv = t >> 6;
  int row0 = (int)blockIdx.x * RPB;

  float lox = (float)(int)qstats[ST_MIN + 0];
  float scx = (float)(NBIN - 1) /
              (float)(int)max(1u, qstats[ST_MAX + 0] - qstats[ST_MIN + 0]);
  float loz = (float)(int)qstats[ST_MIN + 1];
  float scz = (float)(NBIN - 1) /
              (float)(int)max(1u, qstats[ST_MAX + 1] - qstats[ST_MIN + 1]);

  const uint4* px = (const uint4*)(qx + (size_t)row0 * N);
  const uint4* pz = (const uint4*)(qz + (size_t)row0 * N);

  // preload row 0 of this block
  uint4 cxa = px[t * 2], cxb = px[t * 2 + 1];
  uint4 cza = pz[t * 2], czb = pz[t * 2 + 1];

  float pd = 0.f;
  int rsum = 0;

#pragma unroll 1
  for (int r = 0; r < RPB; ++r) {
    // zero hists
#pragma unroll
    for (int i = 0; i < 4; ++i) {
      histX[t + 256 * i] = 0u;
      histZ[t + 256 * i] = 0u;
    }
    // prefetch next row while this row's LDS phases run
    uint4 nxa = cxa, nxb = cxb, nza = cza, nzb = czb;
    if (r + 1 < RPB) {
      const uint4* npx = px + (size_t)(r + 1) * (N / 8);
      const uint4* npz = pz + (size_t)(r + 1) * (N / 8);
      nxa = npx[t * 2];
      nxb = npx[t * 2 + 1];
      nza = npz[t * 2];
      nzb = npz[t * 2 + 1];
    }

    unsigned xw[8] = {cxa.x, cxa.y, cxa.z, cxa.w, cxb.x, cxb.y, cxb.z, cxb.w};
    unsigned zw[8] = {cza.x, cza.y, cza.z, cza.w, czb.x, czb.y, czb.z, czb.w};

    // pairdist partial
#pragma unroll
    for (int c = 0; c < 16; ++c) {
      unsigned qxv = (xw[c >> 1] >> ((c & 1) * 16)) & 0xFFFFu;
      unsigned qzv = (zw[c >> 1] >> ((c & 1) * 16)) & 0xFFFFu;
      // dz-dx = ((qz+.5)/2048 - (qx+.5)/1024) = (qz - 2*qx - 0.5)/2048
      float tv = (float)(int)qzv - 2.0f * (float)(int)qxv - 0.5f;
      pd += tv * tv;
    }
    __syncthreads();  // hist zeroing complete

    // single atomic pass: count AND capture intra-bin offset
    unsigned oxp[8], ozp[8];
#pragma unroll
    for (int c = 0; c < 16; ++c) {
      unsigned qxv = (xw[c >> 1] >> ((c & 1) * 16)) & 0xFFFFu;
      unsigned qzv = (zw[c >> 1] >> ((c & 1) * 16)) & 0xFFFFu;
      unsigned bx = (unsigned)(int)fminf(
          fmaxf(((float)(int)qxv - lox) * scx, 0.0f), (float)(NBIN - 1));
      unsigned bz = (unsigned)(int)fminf(
          fmaxf(((float)(int)qzv - loz) * scz, 0.0f), (float)(NBIN - 1));
      unsigned shx = (bx & 1) * 16, shz = (bz & 1) * 16;
      unsigned ox =
          (atomicAdd(&histX[hsw((int)(bx >> 1))], 1u << shx) >> shx) & 0xFFFFu;
      unsigned oz =
          (atomicAdd(&histZ[hsw((int)(bz >> 1))], 1u << shz) >> shz) & 0xFFFFu;
      if (c & 1) {
        oxp[c >> 1] |= ox << 16;
        ozp[c >> 1] |= oz << 16;
      } else {
        oxp[c >> 1] = ox;
        ozp[c >> 1] = oz;
      }
    }
    __syncthreads();

    // dual exclusive scan: waves 0-1 -> histX, waves 2-3 -> histZ
    {
      unsigned* h = (wv < 2) ? histX : histZ;
      int t2 = t & 127;
      int wb = t2 * 8;
      unsigned run = 0;
#pragma unroll
      for (int c = 0; c < 8; ++c) {
        int w = hsw(wb + c);
        unsigned v = h[w];
        unsigned lo = v & 0xFFFFu;
        h[w] = run | ((run + lo) << 16);
        run += lo + (v >> 16);
      }
      unsigned incl = run;
#pragma unroll
      for (int d = 1; d < 64; d <<= 1) {
        unsigned o = (unsigned)__shfl_up((int)incl, d, 64);
        if (lane >= d) incl += o;
      }
      if (lane == 63) xch[16 + wv] = incl;
      __syncthreads();
      unsigned base = incl - run;              // exclusive within my wave
      if (wv & 1) base += xch[16 + (wv - 1)];  // add lower wave of my hist
      unsigned add = base * 0x10001u;
#pragma unroll
      for (int c = 0; c < 8; ++c) h[hsw(wb + c)] += add;
    }
    __syncthreads();

    // final pass: plain ds_read of scanned bases; |rx-rz| inline
#pragma unroll
    for (int c = 0; c < 16; ++c) {
      unsigned qxv = (xw[c >> 1] >> ((c & 1) * 16)) & 0xFFFFu;
      unsigned qzv = (zw[c >> 1] >> ((c & 1) * 16)) & 0xFFFFu;
      unsigned bx = (unsigned)(int)fminf(
          fmaxf(((float)(int)qxv - lox) * scx, 0.0f), (float)(NBIN - 1));
      unsigned bz = (unsigned)(int)fminf(
          fmaxf(((float)(int)qzv - loz) * scz, 0.0f), (float)(NBIN - 1));
      unsigned shx = (bx & 1) * 16, shz = (bz & 1) * 16;
      unsigned basex = (histX[hsw((int)(bx >> 1))] >> shx) & 0xFFFFu;
      unsigned basez = (histZ[hsw((int)(bz >> 1))] >> shz) & 0xFFFFu;
      int rx = (int)(basex + ((oxp[c >> 1] >> ((c & 1) * 16)) & 0xFFFFu));
      int rz = (int)(basez + ((ozp[c >> 1] >> ((c & 1) * 16)) & 0xFFFFu));
      int d = rx - rz;
      rsum += d < 0 ? -d : d;
    }
    __syncthreads();  // protect hist re-zero next iteration

    cxa = nxa;
    cxb = nxb;
    cza = nza;
    czb = nzb;
  }

  // block reduce + global atomics
#pragma unroll
  for (int d = 32; d; d >>= 1) {
    rsum += __shfl_xor(rsum, d, 64);
    pd += __shfl_xor(pd, d, 64);
  }
  if (lane == 0) {
    xch[wv] = (unsigned)rsum;
    ((float*)xch)[8 + wv] = pd;
  }
  __syncthreads();
  if (t == 0) {
    unsigned long long rtot =
        (unsigned long long)xch[0] + xch[1] + xch[2] + xch[3];
    float ptot = ((float*)xch)[8] + ((float*)xch)[9] + ((float*)xch)[10] +
                 ((float*)xch)[11];
    atomicAdd(rank_acc, rtot);
    atomicAdd(pd_acc, (double)ptot);
  }
}

// ---------------- finalize ----------------
__global__ void finalize_kernel(const unsigned long long* __restrict__ racc,
                                const double* __restrict__ pacc,
                                float* __restrict__ out) {
  double inv = 1.0 / ((double)N * (double)N);
  double rank_loss = (double)(*racc) * inv / 32.0;  // K = 32
  double pd = (*pacc) * inv / (2048.0 * 2048.0);    // undo q scaling
  out[0] = (float)(rank_loss + 0.5 * pd);
  out[1] = (float)rank_loss;
  out[2] = (float)pd;
}

// ---------------- launch ----------------
extern "C" void kernel_launch(void* const* d_in, const int* in_sizes, int n_in,
                              void* d_out, int out_size, void* d_ws,
                              size_t ws_size, hipStream_t stream) {
  (void)in_sizes; (void)n_in; (void)out_size; (void)ws_size;
  const float* x = (const float*)d_in[0];
  const float* z = (const float*)d_in[1];
  float* out = (float*)d_out;

  char* w = (char*)d_ws;
  unsigned short* qx16 = (unsigned short*)(w);             // 32 MB
  unsigned short* qz16 = (unsigned short*)(w + 33554432);  // 32 MB
  __hip_bfloat16* xb = (__hip_bfloat16*)(w + 67108864);    // 4 MB
  __hip_bfloat16* zb = (__hip_bfloat16*)(w + 71303168);    // 0.5 MB
  float* nx = (float*)(w + 71827456);
  float* nz = (float*)(w + 71843840);
  unsigned* qstats = (unsigned*)(w + 71860224);
  unsigned long long* rank_acc = (unsigned long long*)(w + 71860224);
  double* pd_acc = (double*)(w + 71860224 + 8);

  // [0..23] rank_acc, pd_acc, maxx, maxz -> 0 ; [24..31] minx, minz -> ~0
  (void)hipMemsetAsync(w + 71860224, 0, 24, stream);
  (void)hipMemsetAsync(w + 71860224 + 24, 0xFF, 8, stream);

  prep_kernel<<<N, 256, 0, stream>>>(x, z, xb, zb, nx, nz);

  gram_both_kernel<<<NTRI, 256, 0, stream>>>(xb, zb, nx, nz, qx16, qz16,
                                             qstats);

  rank_kernel<<<N / RPB, 256, 0, stream>>>(qx16, qz16, qstats, rank_acc,
                                           pd_acc);

  finalize_kernel<<<1, 1, 0, stream>>>(rank_acc, pd_acc, out);
}

// Round 14
// 183.440 us; speedup vs baseline: 1.1838x; 1.1838x over previous
//
#include <hip/hip_runtime.h>
#include <hip/hip_bf16.h>

// Problem: N=4096, Dx=512, Dz=64.
// out[0]=total, out[1]=rank_loss, out[2]=pairdist_loss (f32).
//
// Pipeline:
//   1. prep: nx[i]=sum x[i]^2 (f32), nz likewise; cast x,z to bf16.
//   2. gram_both (ONE dispatch, FULL 32x32 grid of 128x128 tiles): each
//      block runs the tile pipeline twice — z (K=64) then x (K=512).
//      NO symmetry: r13 showed per-K-iter cost ~constant (~2000+ cyc)
//      regardless of occupancy/tile size; the m97-verified config (full
//      1024-block grid, 4 blocks/CU, identical inner loop) achieves
//      ~736 cyc/iter. Full grid doubles cheap MFMA work (~4 us) but
//      restores the block-level parallelism that hides the drain, and
//      deletes the mirror epilogue (2 barriers + LDS round-trip/tile).
//      bf16 MFMA, dbuf global_load_lds staging, LDS-staged coalesced
//      uint4 dist writes. q0=min(floor(d*qscale),65535), qscale 1024 (x)
//      / 2048 (z). Global off-diag min/max: 2 atomics/tile.
//   3. rank kernel: 1024 blocks x 256 thr, 4 rows/block, register
//      prefetch; global-normalized 11-bit bins; ds_add_rtn count+offset
//      pass; dual scan; plain ds_read final pass; |rx-rz| inline.
//   4. finalize: 3 scalars.

#define N 4096
#define DX 512
#define DZ 64
#define NBIN 2048
#define NWRD (NBIN / 2)
#define RPB 4

typedef __attribute__((ext_vector_type(8))) short short8;
typedef __attribute__((ext_vector_type(4))) float float4v;

// stats word layout (u32 index into qstats base):
//   [0..1] rank_acc (u64)  [2..3] pd_acc (double)
//   [4] maxx [5] maxz      [6] minx [7] minz
#define ST_MAX 4
#define ST_MIN 6

// ---------------- async 16B global -> LDS ----------------
__device__ __forceinline__ void async16(const void* g, void* l) {
  __builtin_amdgcn_global_load_lds(
      (const __attribute__((address_space(1))) unsigned int*)(g),
      (__attribute__((address_space(3))) unsigned int*)(l), 16, 0, 0);
}

// ---------------- prep: norms + bf16 casts ----------------
__global__ __launch_bounds__(256) void prep_kernel(
    const float* __restrict__ x, const float* __restrict__ z,
    __hip_bfloat16* __restrict__ xb, __hip_bfloat16* __restrict__ zb,
    float* __restrict__ nx, float* __restrict__ nz) {
  int row = blockIdx.x;
  int tid = threadIdx.x;
  __shared__ float red[256];

  float sx = 0.f;
  for (int c = tid; c < DX; c += 256) {
    float v = x[(size_t)row * DX + c];
    xb[(size_t)row * DX + c] = __float2bfloat16(v);
    sx += v * v;
  }
  red[tid] = sx;
  __syncthreads();
  for (int s = 128; s > 0; s >>= 1) {
    if (tid < s) red[tid] += red[tid + s];
    __syncthreads();
  }
  if (tid == 0) nx[row] = red[0];
  __syncthreads();

  float sz = 0.f;
  if (tid < DZ) {
    float v = z[(size_t)row * DZ + tid];
    zb[(size_t)row * DZ + tid] = __float2bfloat16(v);
    sz = v * v;
  }
  red[tid] = sz;
  __syncthreads();
  for (int s = 128; s > 0; s >>= 1) {
    if (tid < s) red[tid] += red[tid + s];
    __syncthreads();
  }
  if (tid == 0) nz[row] = red[0];
}

// ------- bf16 MFMA Gram tile pipeline (device fn, run per matrix) --------
#define TILE 128
#define BK 32
#define PADW 132  // ctile row stride in u16 (66 words)

__device__ __forceinline__ void gram_tile(
    const __hip_bfloat16* __restrict__ Abf, const float* __restrict__ norms,
    unsigned short* __restrict__ distq, int K, float qscale,
    unsigned* __restrict__ qstats, int slot, int by, int bx, char* smem,
    unsigned* mmx) {
  unsigned short* ctile = (unsigned short*)smem;

  int tid = threadIdx.x;
  int wave = tid >> 6, lane = tid & 63;
  int wr = wave >> 1, wc = wave & 1;
  int quad = lane >> 4, l15 = lane & 15;

  int rowBase = by * TILE;
  int colBase = bx * TILE;

  float4v acc[4][4];
#pragma unroll
  for (int mi = 0; mi < 4; ++mi)
#pragma unroll
    for (int ni = 0; ni < 4; ++ni) {
      float4v zv = {0.f, 0.f, 0.f, 0.f};
      acc[mi][ni] = zv;
    }

  const char* Ab = (const char*)Abf;
  const size_t rb = (size_t)K * 2;  // row bytes
  int chunk0 = wave * 2, chunk1 = wave * 2 + 1;
  int rl = lane >> 2;        // row within a 16-row chunk (4 lanes/row)
  int cl = (lane & 3) * 16;  // byte col within 64B row

  // stage K-chunk kc into buffer b (byte-offset derived LDS pointers)
  auto stage = [&](int kc, int b) {
    const char* base = Ab + (size_t)kc * 2 + cl;
    short* sA = (short*)(smem + b * 16384);
    short* sB = (short*)(smem + b * 16384 + 8192);
    async16(base + (size_t)(rowBase + chunk0 * 16 + rl) * rb,
            &sA[chunk0 * 512]);
    async16(base + (size_t)(rowBase + chunk1 * 16 + rl) * rb,
            &sA[chunk1 * 512]);
    async16(base + (size_t)(colBase + chunk0 * 16 + rl) * rb,
            &sB[chunk0 * 512]);
    async16(base + (size_t)(colBase + chunk1 * 16 + rl) * rb,
            &sB[chunk1 * 512]);
  };

  stage(0, 0);  // preload first chunk
  int ib = 0;
  for (int kc = 0; kc < K; kc += BK, ib ^= 1) {
    __syncthreads();  // drains current buf's staging; prev readers done
    if (kc + BK < K) stage(kc + BK, ib ^ 1);  // issued post-barrier

    const short* As = (const short*)(smem + ib * 16384);
    const short* Bs = (const short*)(smem + ib * 16384 + 8192);
    short8 a[4], b[4];
#pragma unroll
    for (int mi = 0; mi < 4; ++mi)
      a[mi] = *(const short8*)(&As[(wr * 64 + mi * 16 + l15) * BK + quad * 8]);
#pragma unroll
    for (int ni = 0; ni < 4; ++ni)
      b[ni] = *(const short8*)(&Bs[(wc * 64 + ni * 16 + l15) * BK + quad * 8]);
#pragma unroll
    for (int mi = 0; mi < 4; ++mi)
#pragma unroll
      for (int ni = 0; ni < 4; ++ni)
        acc[mi][ni] = __builtin_amdgcn_mfma_f32_16x16x32_bf16(
            a[mi], b[ni], acc[mi][ni], 0, 0, 0);
  }
  __syncthreads();  // all staging reads done before ctile aliasing write

  // ---- quantize: stage [row][col] in LDS ----
  unsigned mn = 0xFFFFu, mx = 0u;
#pragma unroll
  for (int mi = 0; mi < 4; ++mi) {
#pragma unroll
    for (int ni = 0; ni < 4; ++ni) {
      int colL = wc * 64 + ni * 16 + l15;
      float ncol = norms[colBase + colL];
#pragma unroll
      for (int r = 0; r < 4; ++r) {
        int rowL = wr * 64 + mi * 16 + quad * 4 + r;
        int row = rowBase + rowL;
        float sq = norms[row] + ncol - 2.0f * acc[mi][ni][r];
        float d = sq > 0.f ? sqrtf(sq) : 0.f;
        if (row == colBase + colL) d = 0.f;
        unsigned q = (unsigned)(d * qscale);
        q = q > 65535u ? 65535u : q;
        ctile[rowL * PADW + colL] = (unsigned short)q;
        mx = max(mx, q);
        mn = min(mn, (row == colBase + colL) ? 0xFFFFu : q);
      }
    }
  }
  __syncthreads();

  // ---- coalesced uint4 row writes from ctile[row][col] ----
  {
    const unsigned* cw = (const unsigned*)ctile;  // word rows, stride 66
    int i0 = tid >> 4, k4 = (tid & 15) * 4;
#pragma unroll
    for (int s = 0; s < 8; ++s) {
      int i = s * 16 + i0;
      int wb = i * (PADW / 2) + k4;
      uint4 v;
      v.x = cw[wb + 0];
      v.y = cw[wb + 1];
      v.z = cw[wb + 2];
      v.w = cw[wb + 3];
      *(uint4*)(distq + (size_t)(rowBase + i) * N + colBase + (tid & 15) * 8) =
          v;
    }
  }

  // ---- block-level min/max reduce -> 2 device atomics per tile ----
#pragma unroll
  for (int d = 32; d; d >>= 1) {
    mn = min(mn, (unsigned)__shfl_xor((int)mn, d, 64));
    mx = max(mx, (unsigned)__shfl_xor((int)mx, d, 64));
  }
  __syncthreads();  // ctile reads done; mmx reuse safe
  if (lane == 0) {
    mmx[wave] = mn;
    mmx[4 + wave] = mx;
  }
  __syncthreads();
  if (tid == 0) {
    unsigned bmn = min(min(mmx[0], mmx[1]), min(mmx[2], mmx[3]));
    unsigned bmx = max(max(mmx[4], mmx[5]), max(mmx[6], mmx[7]));
    atomicMin(&qstats[ST_MIN + slot], bmn);
    atomicMax(&qstats[ST_MAX + slot], bmx);
  }
}

__global__ __launch_bounds__(256) void gram_both_kernel(
    const __hip_bfloat16* __restrict__ xb, const __hip_bfloat16* __restrict__ zb,
    const float* __restrict__ nx, const float* __restrict__ nz,
    unsigned short* __restrict__ qx16, unsigned short* __restrict__ qz16,
    unsigned* __restrict__ qstats) {
  __shared__ alignas(16) char smem[TILE * PADW * 2];  // 33 KB
  __shared__ unsigned mmx[8];

  int by = (int)blockIdx.y, bx = (int)blockIdx.x;

  // z tile first (cheap, K=64), then x tile (K=512)
  gram_tile(zb, nz, qz16, DZ, 2048.0f, qstats, 1, by, bx, smem, mmx);
  __syncthreads();
  gram_tile(xb, nx, qx16, DX, 1024.0f, qstats, 0, by, bx, smem, mmx);
}

// ---------------- counting-based per-row ranks (4 rows / block) ----------
__device__ __forceinline__ int hsw(int w) { return w ^ ((w >> 5) & 31); }

__global__ __launch_bounds__(256) void rank_kernel(
    const unsigned short* __restrict__ qx,
    const unsigned short* __restrict__ qz,
    const unsigned* __restrict__ qstats,
    unsigned long long* __restrict__ rank_acc, double* __restrict__ pd_acc) {
  __shared__ unsigned histX[NWRD];  // 4 KB
  __shared__ unsigned histZ[NWRD];  // 4 KB
  __shared__ unsigned xch[32];

  int t = threadIdx.x, lane = t & 63, wv = t >> 6;
  int row0 = (int)blockIdx.x * RPB;

  float lox = (float)(int)qstats[ST_MIN + 0];
  float scx = (float)(NBIN - 1) /
              (float)(int)max(1u, qstats[ST_MAX + 0] - qstats[ST_MIN + 0]);
  float loz = (float)(int)qstats[ST_MIN + 1];
  float scz = (float)(NBIN - 1) /
              (float)(int)max(1u, qstats[ST_MAX + 1] - qstats[ST_MIN + 1]);

  const uint4* px = (const uint4*)(qx + (size_t)row0 * N);
  const uint4* pz = (const uint4*)(qz + (size_t)row0 * N);

  // preload row 0 of this block
  uint4 cxa = px[t * 2], cxb = px[t * 2 + 1];
  uint4 cza = pz[t * 2], czb = pz[t * 2 + 1];

  float pd = 0.f;
  int rsum = 0;

#pragma unroll 1
  for (int r = 0; r < RPB; ++r) {
    // zero hists
#pragma unroll
    for (int i = 0; i < 4; ++i) {
      histX[t + 256 * i] = 0u;
      histZ[t + 256 * i] = 0u;
    }
    // prefetch next row while this row's LDS phases run
    uint4 nxa = cxa, nxb = cxb, nza = cza, nzb = czb;
    if (r + 1 < RPB) {
      const uint4* npx = px + (size_t)(r + 1) * (N / 8);
      const uint4* npz = pz + (size_t)(r + 1) * (N / 8);
      nxa = npx[t * 2];
      nxb = npx[t * 2 + 1];
      nza = npz[t * 2];
      nzb = npz[t * 2 + 1];
    }

    unsigned xw[8] = {cxa.x, cxa.y, cxa.z, cxa.w, cxb.x, cxb.y, cxb.z, cxb.w};
    unsigned zw[8] = {cza.x, cza.y, cza.z, cza.w, czb.x, czb.y, czb.z, czb.w};

    // pairdist partial
#pragma unroll
    for (int c = 0; c < 16; ++c) {
      unsigned qxv = (xw[c >> 1] >> ((c & 1) * 16)) & 0xFFFFu;
      unsigned qzv = (zw[c >> 1] >> ((c & 1) * 16)) & 0xFFFFu;
      // dz-dx = ((qz+.5)/2048 - (qx+.5)/1024) = (qz - 2*qx - 0.5)/2048
      float tv = (float)(int)qzv - 2.0f * (float)(int)qxv - 0.5f;
      pd += tv * tv;
    }
    __syncthreads();  // hist zeroing complete

    // single atomic pass: count AND capture intra-bin offset
    unsigned oxp[8], ozp[8];
#pragma unroll
    for (int c = 0; c < 16; ++c) {
      unsigned qxv = (xw[c >> 1] >> ((c & 1) * 16)) & 0xFFFFu;
      unsigned qzv = (zw[c >> 1] >> ((c & 1) * 16)) & 0xFFFFu;
      unsigned bx = (unsigned)(int)fminf(
          fmaxf(((float)(int)qxv - lox) * scx, 0.0f), (float)(NBIN - 1));
      unsigned bz = (unsigned)(int)fminf(
          fmaxf(((float)(int)qzv - loz) * scz, 0.0f), (float)(NBIN - 1));
      unsigned shx = (bx & 1) * 16, shz = (bz & 1) * 16;
      unsigned ox =
          (atomicAdd(&histX[hsw((int)(bx >> 1))], 1u << shx) >> shx) & 0xFFFFu;
      unsigned oz =
          (atomicAdd(&histZ[hsw((int)(bz >> 1))], 1u << shz) >> shz) & 0xFFFFu;
      if (c & 1) {
        oxp[c >> 1] |= ox << 16;
        ozp[c >> 1] |= oz << 16;
      } else {
        oxp[c >> 1] = ox;
        ozp[c >> 1] = oz;
      }
    }
    __syncthreads();

    // dual exclusive scan: waves 0-1 -> histX, waves 2-3 -> histZ
    {
      unsigned* h = (wv < 2) ? histX : histZ;
      int t2 = t & 127;
      int wb = t2 * 8;
      unsigned run = 0;
#pragma unroll
      for (int c = 0; c < 8; ++c) {
        int w = hsw(wb + c);
        unsigned v = h[w];
        unsigned lo = v & 0xFFFFu;
        h[w] = run | ((run + lo) << 16);
        run += lo + (v >> 16);
      }
      unsigned incl = run;
#pragma unroll
      for (int d = 1; d < 64; d <<= 1) {
        unsigned o = (unsigned)__shfl_up((int)incl, d, 64);
        if (lane >= d) incl += o;
      }
      if (lane == 63) xch[16 + wv] = incl;
      __syncthreads();
      unsigned base = incl - run;              // exclusive within my wave
      if (wv & 1) base += xch[16 + (wv - 1)];  // add lower wave of my hist
      unsigned add = base * 0x10001u;
#pragma unroll
      for (int c = 0; c < 8; ++c) h[hsw(wb + c)] += add;
    }
    __syncthreads();

    // final pass: plain ds_read of scanned bases; |rx-rz| inline
#pragma unroll
    for (int c = 0; c < 16; ++c) {
      unsigned qxv = (xw[c >> 1] >> ((c & 1) * 16)) & 0xFFFFu;
      unsigned qzv = (zw[c >> 1] >> ((c & 1) * 16)) & 0xFFFFu;
      unsigned bx = (unsigned)(int)fminf(
          fmaxf(((float)(int)qxv - lox) * scx, 0.0f), (float)(NBIN - 1));
      unsigned bz = (unsigned)(int)fminf(
          fmaxf(((float)(int)qzv - loz) * scz, 0.0f), (float)(NBIN - 1));
      unsigned shx = (bx & 1) * 16, shz = (bz & 1) * 16;
      unsigned basex = (histX[hsw((int)(bx >> 1))] >> shx) & 0xFFFFu;
      unsigned basez = (histZ[hsw((int)(bz >> 1))] >> shz) & 0xFFFFu;
      int rx = (int)(basex + ((oxp[c >> 1] >> ((c & 1) * 16)) & 0xFFFFu));
      int rz = (int)(basez + ((ozp[c >> 1] >> ((c & 1) * 16)) & 0xFFFFu));
      int d = rx - rz;
      rsum += d < 0 ? -d : d;
    }
    __syncthreads();  // protect hist re-zero next iteration

    cxa = nxa;
    cxb = nxb;
    cza = nza;
    czb = nzb;
  }

  // block reduce + global atomics
#pragma unroll
  for (int d = 32; d; d >>= 1) {
    rsum += __shfl_xor(rsum, d, 64);
    pd += __shfl_xor(pd, d, 64);
  }
  if (lane == 0) {
    xch[wv] = (unsigned)rsum;
    ((float*)xch)[8 + wv] = pd;
  }
  __syncthreads();
  if (t == 0) {
    unsigned long long rtot =
        (unsigned long long)xch[0] + xch[1] + xch[2] + xch[3];
    float ptot = ((float*)xch)[8] + ((float*)xch)[9] + ((float*)xch)[10] +
                 ((float*)xch)[11];
    atomicAdd(rank_acc, rtot);
    atomicAdd(pd_acc, (double)ptot);
  }
}

// ---------------- finalize ----------------
__global__ void finalize_kernel(const unsigned long long* __restrict__ racc,
                                const double* __restrict__ pacc,
                                float* __restrict__ out) {
  double inv = 1.0 / ((double)N * (double)N);
  double rank_loss = (double)(*racc) * inv / 32.0;  // K = 32
  double pd = (*pacc) * inv / (2048.0 * 2048.0);    // undo q scaling
  out[0] = (float)(rank_loss + 0.5 * pd);
  out[1] = (float)rank_loss;
  out[2] = (float)pd;
}

// ---------------- launch ----------------
extern "C" void kernel_launch(void* const* d_in, const int* in_sizes, int n_in,
                              void* d_out, int out_size, void* d_ws,
                              size_t ws_size, hipStream_t stream) {
  (void)in_sizes; (void)n_in; (void)out_size; (void)ws_size;
  const float* x = (const float*)d_in[0];
  const float* z = (const float*)d_in[1];
  float* out = (float*)d_out;

  char* w = (char*)d_ws;
  unsigned short* qx16 = (unsigned short*)(w);             // 32 MB
  unsigned short* qz16 = (unsigned short*)(w + 33554432);  // 32 MB
  __hip_bfloat16* xb = (__hip_bfloat16*)(w + 67108864);    // 4 MB
  __hip_bfloat16* zb = (__hip_bfloat16*)(w + 71303168);    // 0.5 MB
  float* nx = (float*)(w + 71827456);
  float* nz = (float*)(w + 71843840);
  unsigned* qstats = (unsigned*)(w + 71860224);
  unsigned long long* rank_acc = (unsigned long long*)(w + 71860224);
  double* pd_acc = (double*)(w + 71860224 + 8);

  // [0..23] rank_acc, pd_acc, maxx, maxz -> 0 ; [24..31] minx, minz -> ~0
  (void)hipMemsetAsync(w + 71860224, 0, 24, stream);
  (void)hipMemsetAsync(w + 71860224 + 24, 0xFF, 8, stream);

  prep_kernel<<<N, 256, 0, stream>>>(x, z, xb, zb, nx, nz);

  dim3 ggrid(N / TILE, N / TILE);
  gram_both_kernel<<<ggrid, 256, 0, stream>>>(xb, zb, nx, nz, qx16, qz16,
                                              qstats);

  rank_kernel<<<N / RPB, 256, 0, stream>>>(qx16, qz16, qstats, rank_acc,
                                           pd_acc);

  finalize_kernel<<<1, 1, 0, stream>>>(rank_acc, pd_acc, out);
}

// Round 15
// 174.048 us; speedup vs baseline: 1.2476x; 1.0540x over previous
//
#include <hip/hip_runtime.h>
#include <hip/hip_bf16.h>

// Problem: N=4096, Dx=512, Dz=64.
// out[0]=total, out[1]=rank_loss, out[2]=pairdist_loss (f32).
//
// Pipeline:
//   1. prep (barrier-free): one wave per row; float4 loads, shuffle-only
//      reductions, packed bf16 ushort4 stores. Also zero-inits qstats
//      (incl. rank/pd accumulators and rank's done-counter) — replaces the
//      r12 block-reduction prep (~16 barriers/row) and both memset nodes.
//   2. gram_both (r12-measured-best): 528 symmetric triangular 128-tiles,
//      each block does z-tile (K=64) then x-tile (K=512). bf16 MFMA, dbuf
//      global_load_lds staging, LDS-staged coalesced uint4 dist writes,
//      mirror tile via LDS transpose restage. q0=min(floor(d*qscale),65535),
//      qscale 1024 (x) / 2048 (z). min/max qstats: 2 atomics/tile.
//   3. rank kernel: 1024 blocks x 256 thr, 4 rows/block, register
//      prefetch; global-normalized 11-bit bins; ds_add_rtn count+offset
//      pass; dual scan; plain ds_read final pass; |rx-rz| inline.
//      LAST block (done-counter) computes the 3 output scalars inline —
//      finalize kernel removed.

#define N 4096
#define DX 512
#define DZ 64
#define NBIN 2048
#define NWRD (NBIN / 2)
#define RPB 4

typedef __attribute__((ext_vector_type(8))) short short8;
typedef __attribute__((ext_vector_type(4))) float float4v;

// qstats word layout (u32 index):
//   [0..1] rank_acc (u64)  [2..3] pd_acc (double)
//   [4] maxx [5] maxz      [6] minx [7] minz    [8] done-counter
#define ST_MAX 4
#define ST_MIN 6
#define ST_DONE 8

// ---------------- async 16B global -> LDS ----------------
__device__ __forceinline__ void async16(const void* g, void* l) {
  __builtin_amdgcn_global_load_lds(
      (const __attribute__((address_space(1))) unsigned int*)(g),
      (__attribute__((address_space(3))) unsigned int*)(l), 16, 0, 0);
}

// ---------------- prep: barrier-free wave-per-row ----------------
__global__ __launch_bounds__(256) void prep_kernel(
    const float* __restrict__ x, const float* __restrict__ z,
    __hip_bfloat16* __restrict__ xb, __hip_bfloat16* __restrict__ zb,
    float* __restrict__ nx, float* __restrict__ nz,
    unsigned* __restrict__ qstats) {
  int tid = threadIdx.x;
  // init qstats once (block 0): accumulators/max/done=0, min=~0
  if (blockIdx.x == 0 && tid < 9)
    qstats[tid] = (tid == 6 || tid == 7) ? 0xFFFFFFFFu : 0u;

  int lane = tid & 63;
  int row = (int)blockIdx.x * 4 + (tid >> 6);  // one wave per row

  // ---- x: 512 floats = 2 float4/lane ----
  const float4* xr = (const float4*)(x + (size_t)row * DX);
  float4 a = xr[lane];
  float4 b = xr[lane + 64];
  float s = a.x * a.x + a.y * a.y + a.z * a.z + a.w * a.w +
            b.x * b.x + b.y * b.y + b.z * b.z + b.w * b.w;
#pragma unroll
  for (int d = 32; d; d >>= 1) s += __shfl_xor(s, d, 64);
  if (lane == 0) nx[row] = s;

  ushort4 pa, pb;
  pa.x = __bfloat16_as_ushort(__float2bfloat16(a.x));
  pa.y = __bfloat16_as_ushort(__float2bfloat16(a.y));
  pa.z = __bfloat16_as_ushort(__float2bfloat16(a.z));
  pa.w = __bfloat16_as_ushort(__float2bfloat16(a.w));
  pb.x = __bfloat16_as_ushort(__float2bfloat16(b.x));
  pb.y = __bfloat16_as_ushort(__float2bfloat16(b.y));
  pb.z = __bfloat16_as_ushort(__float2bfloat16(b.z));
  pb.w = __bfloat16_as_ushort(__float2bfloat16(b.w));
  ushort4* xbo = (ushort4*)(xb + (size_t)row * DX);
  xbo[lane] = pa;
  xbo[lane + 64] = pb;

  // ---- z: 64 floats, lanes 0-15 hold one float4 each ----
  float4 c = {0.f, 0.f, 0.f, 0.f};
  if (lane < 16) c = ((const float4*)(z + (size_t)row * DZ))[lane];
  float sz = c.x * c.x + c.y * c.y + c.z * c.z + c.w * c.w;
#pragma unroll
  for (int d = 32; d; d >>= 1) sz += __shfl_xor(sz, d, 64);
  if (lane == 0) nz[row] = sz;
  if (lane < 16) {
    ushort4 pc;
    pc.x = __bfloat16_as_ushort(__float2bfloat16(c.x));
    pc.y = __bfloat16_as_ushort(__float2bfloat16(c.y));
    pc.z = __bfloat16_as_ushort(__float2bfloat16(c.z));
    pc.w = __bfloat16_as_ushort(__float2bfloat16(c.w));
    ((ushort4*)(zb + (size_t)row * DZ))[lane] = pc;
  }
}

// ------- bf16 MFMA Gram tile pipeline (r12-measured-best config) ---------
#define TILE 128
#define BK 32
#define PADW 132  // ctile row stride in u16 (66 words, 8B-aligned b64)
#define NT 32
#define NTRI 528

__device__ __forceinline__ void gram_tile(
    const __hip_bfloat16* __restrict__ Abf, const float* __restrict__ norms,
    unsigned short* __restrict__ distq, int K, float qscale,
    unsigned* __restrict__ qstats, int slot, int by, int bx, char* smem,
    unsigned* mmx) {
  unsigned short* ctile = (unsigned short*)smem;

  int tid = threadIdx.x;
  int wave = tid >> 6, lane = tid & 63;
  int wr = wave >> 1, wc = wave & 1;
  int quad = lane >> 4, l15 = lane & 15;

  int rowBase = by * TILE;
  int colBase = bx * TILE;

  float4v acc[4][4];
#pragma unroll
  for (int mi = 0; mi < 4; ++mi)
#pragma unroll
    for (int ni = 0; ni < 4; ++ni) {
      float4v zv = {0.f, 0.f, 0.f, 0.f};
      acc[mi][ni] = zv;
    }

  const char* Ab = (const char*)Abf;
  const size_t rb = (size_t)K * 2;
  int chunk0 = wave * 2, chunk1 = wave * 2 + 1;
  int rl = lane >> 2;
  int cl = (lane & 3) * 16;

  auto stage = [&](int kc, int b) {
    const char* base = Ab + (size_t)kc * 2 + cl;
    short* sA = (short*)(smem + b * 16384);
    short* sB = (short*)(smem + b * 16384 + 8192);
    async16(base + (size_t)(rowBase + chunk0 * 16 + rl) * rb,
            &sA[chunk0 * 512]);
    async16(base + (size_t)(rowBase + chunk1 * 16 + rl) * rb,
            &sA[chunk1 * 512]);
    async16(base + (size_t)(colBase + chunk0 * 16 + rl) * rb,
            &sB[chunk0 * 512]);
    async16(base + (size_t)(colBase + chunk1 * 16 + rl) * rb,
            &sB[chunk1 * 512]);
  };

  stage(0, 0);
  int ib = 0;
  for (int kc = 0; kc < K; kc += BK, ib ^= 1) {
    __syncthreads();
    if (kc + BK < K) stage(kc + BK, ib ^ 1);

    const short* As = (const short*)(smem + ib * 16384);
    const short* Bs = (const short*)(smem + ib * 16384 + 8192);
    short8 a[4], b[4];
#pragma unroll
    for (int mi = 0; mi < 4; ++mi)
      a[mi] = *(const short8*)(&As[(wr * 64 + mi * 16 + l15) * BK + quad * 8]);
#pragma unroll
    for (int ni = 0; ni < 4; ++ni)
      b[ni] = *(const short8*)(&Bs[(wc * 64 + ni * 16 + l15) * BK + quad * 8]);
#pragma unroll
    for (int mi = 0; mi < 4; ++mi)
#pragma unroll
      for (int ni = 0; ni < 4; ++ni)
        acc[mi][ni] = __builtin_amdgcn_mfma_f32_16x16x32_bf16(
            a[mi], b[ni], acc[mi][ni], 0, 0, 0);
  }
  __syncthreads();

  // quantize: stage [row][col] in LDS + keep packed u64 per column
  unsigned mn = 0xFFFFu, mx = 0u;
  unsigned long long qp[4][4];
#pragma unroll
  for (int mi = 0; mi < 4; ++mi) {
#pragma unroll
    for (int ni = 0; ni < 4; ++ni) {
      int colL = wc * 64 + ni * 16 + l15;
      float ncol = norms[colBase + colL];
      unsigned long long pk = 0ull;
#pragma unroll
      for (int r = 0; r < 4; ++r) {
        int rowL = wr * 64 + mi * 16 + quad * 4 + r;
        int row = rowBase + rowL;
        float sq = norms[row] + ncol - 2.0f * acc[mi][ni][r];
        float d = sq > 0.f ? sqrtf(sq) : 0.f;
        if (row == colBase + colL) d = 0.f;
        unsigned q = (unsigned)(d * qscale);
        q = q > 65535u ? 65535u : q;
        ctile[rowL * PADW + colL] = (unsigned short)q;
        pk |= (unsigned long long)q << (16 * r);
        mx = max(mx, q);
        mn = min(mn, (row == colBase + colL) ? 0xFFFFu : q);
      }
      qp[mi][ni] = pk;
    }
  }
  __syncthreads();

  // pass A: upper tile, coalesced uint4 rows
  {
    const unsigned* cw = (const unsigned*)ctile;
    int i0 = tid >> 4, k4 = (tid & 15) * 4;
#pragma unroll
    for (int s = 0; s < 8; ++s) {
      int i = s * 16 + i0;
      int wb = i * (PADW / 2) + k4;
      uint4 v;
      v.x = cw[wb + 0];
      v.y = cw[wb + 1];
      v.z = cw[wb + 2];
      v.w = cw[wb + 3];
      *(uint4*)(distq + (size_t)(rowBase + i) * N + colBase + (tid & 15) * 8) =
          v;
    }
  }

  // pass B: mirror tile via transposed restage (off-diag only)
  if (by != bx) {
    __syncthreads();
#pragma unroll
    for (int mi = 0; mi < 4; ++mi)
#pragma unroll
      for (int ni = 0; ni < 4; ++ni) {
        int colL = wc * 64 + ni * 16 + l15;
        int rowL0 = wr * 64 + mi * 16 + quad * 4;
        *(unsigned long long*)&ctile[colL * PADW + rowL0] = qp[mi][ni];
      }
    __syncthreads();
    const unsigned* cw = (const unsigned*)ctile;
    int j0 = tid >> 4, k4 = (tid & 15) * 4;
#pragma unroll
    for (int s = 0; s < 8; ++s) {
      int j = s * 16 + j0;
      int wb = j * (PADW / 2) + k4;
      uint4 v;
      v.x = cw[wb + 0];
      v.y = cw[wb + 1];
      v.z = cw[wb + 2];
      v.w = cw[wb + 3];
      *(uint4*)(distq + (size_t)(colBase + j) * N + rowBase + (tid & 15) * 8) =
          v;
    }
  }

  // block-level min/max reduce -> 2 device atomics per tile
#pragma unroll
  for (int d = 32; d; d >>= 1) {
    mn = min(mn, (unsigned)__shfl_xor((int)mn, d, 64));
    mx = max(mx, (unsigned)__shfl_xor((int)mx, d, 64));
  }
  __syncthreads();
  if (lane == 0) {
    mmx[wave] = mn;
    mmx[4 + wave] = mx;
  }
  __syncthreads();
  if (tid == 0) {
    unsigned bmn = min(min(mmx[0], mmx[1]), min(mmx[2], mmx[3]));
    unsigned bmx = max(max(mmx[4], mmx[5]), max(mmx[6], mmx[7]));
    atomicMin(&qstats[ST_MIN + slot], bmn);
    atomicMax(&qstats[ST_MAX + slot], bmx);
  }
}

__global__ __launch_bounds__(256) void gram_both_kernel(
    const __hip_bfloat16* __restrict__ xb, const __hip_bfloat16* __restrict__ zb,
    const float* __restrict__ nx, const float* __restrict__ nz,
    unsigned short* __restrict__ qx16, unsigned short* __restrict__ qz16,
    unsigned* __restrict__ qstats) {
  __shared__ alignas(16) char smem[TILE * PADW * 2];  // 33 KB
  __shared__ unsigned mmx[8];

  // compact upper-triangular decode: row-major rows by=0..31, len 32-by
  int idx = (int)blockIdx.x;
  int by = (int)((65.0f - sqrtf(4225.0f - 8.0f * (float)idx)) * 0.5f);
  while (((by + 1) * (65 - (by + 1))) / 2 <= idx) ++by;
  while ((by * (65 - by)) / 2 > idx) --by;
  int bx = by + (idx - (by * (65 - by)) / 2);

  gram_tile(zb, nz, qz16, DZ, 2048.0f, qstats, 1, by, bx, smem, mmx);
  __syncthreads();
  gram_tile(xb, nx, qx16, DX, 1024.0f, qstats, 0, by, bx, smem, mmx);
}

// ---------------- counting-based per-row ranks (4 rows / block) ----------
__device__ __forceinline__ int hsw(int w) { return w ^ ((w >> 5) & 31); }

__global__ __launch_bounds__(256) void rank_kernel(
    const unsigned short* __restrict__ qx,
    const unsigned short* __restrict__ qz, unsigned* __restrict__ qstats,
    float* __restrict__ out) {
  __shared__ unsigned histX[NWRD];
  __shared__ unsigned histZ[NWRD];
  __shared__ unsigned xch[32];

  unsigned long long* rank_acc = (unsigned long long*)qstats;
  double* pd_acc = (double*)(qstats + 2);

  int t = threadIdx.x, lane = t & 63, wv = t >> 6;
  int row0 = (int)blockIdx.x * RPB;

  float lox = (float)(int)qstats[ST_MIN + 0];
  float scx = (float)(NBIN - 1) /
              (float)(int)max(1u, qstats[ST_MAX + 0] - qstats[ST_MIN + 0]);
  float loz = (float)(int)qstats[ST_MIN + 1];
  float scz = (float)(NBIN - 1) /
              (float)(int)max(1u, qstats[ST_MAX + 1] - qstats[ST_MIN + 1]);

  const uint4* px = (const uint4*)(qx + (size_t)row0 * N);
  const uint4* pz = (const uint4*)(qz + (size_t)row0 * N);

  uint4 cxa = px[t * 2], cxb = px[t * 2 + 1];
  uint4 cza = pz[t * 2], czb = pz[t * 2 + 1];

  float pd = 0.f;
  int rsum = 0;

#pragma unroll 1
  for (int r = 0; r < RPB; ++r) {
#pragma unroll
    for (int i = 0; i < 4; ++i) {
      histX[t + 256 * i] = 0u;
      histZ[t + 256 * i] = 0u;
    }
    uint4 nxa = cxa, nxb = cxb, nza = cza, nzb = czb;
    if (r + 1 < RPB) {
      const uint4* npx = px + (size_t)(r + 1) * (N / 8);
      const uint4* npz = pz + (size_t)(r + 1) * (N / 8);
      nxa = npx[t * 2];
      nxb = npx[t * 2 + 1];
      nza = npz[t * 2];
      nzb = npz[t * 2 + 1];
    }

    unsigned xw[8] = {cxa.x, cxa.y, cxa.z, cxa.w, cxb.x, cxb.y, cxb.z, cxb.w};
    unsigned zw[8] = {cza.x, cza.y, cza.z, cza.w, czb.x, czb.y, czb.z, czb.w};

#pragma unroll
    for (int c = 0; c < 16; ++c) {
      unsigned qxv = (xw[c >> 1] >> ((c & 1) * 16)) & 0xFFFFu;
      unsigned qzv = (zw[c >> 1] >> ((c & 1) * 16)) & 0xFFFFu;
      // dz-dx = (qz - 2*qx - 0.5)/2048
      float tv = (float)(int)qzv - 2.0f * (float)(int)qxv - 0.5f;
      pd += tv * tv;
    }
    __syncthreads();

    unsigned oxp[8], ozp[8];
#pragma unroll
    for (int c = 0; c < 16; ++c) {
      unsigned qxv = (xw[c >> 1] >> ((c & 1) * 16)) & 0xFFFFu;
      unsigned qzv = (zw[c >> 1] >> ((c & 1) * 16)) & 0xFFFFu;
      unsigned bx = (unsigned)(int)fminf(
          fmaxf(((float)(int)qxv - lox) * scx, 0.0f), (float)(NBIN - 1));
      unsigned bz = (unsigned)(int)fminf(
          fmaxf(((float)(int)qzv - loz) * scz, 0.0f), (float)(NBIN - 1));
      unsigned shx = (bx & 1) * 16, shz = (bz & 1) * 16;
      unsigned ox =
          (atomicAdd(&histX[hsw((int)(bx >> 1))], 1u << shx) >> shx) & 0xFFFFu;
      unsigned oz =
          (atomicAdd(&histZ[hsw((int)(bz >> 1))], 1u << shz) >> shz) & 0xFFFFu;
      if (c & 1) {
        oxp[c >> 1] |= ox << 16;
        ozp[c >> 1] |= oz << 16;
      } else {
        oxp[c >> 1] = ox;
        ozp[c >> 1] = oz;
      }
    }
    __syncthreads();

    {
      unsigned* h = (wv < 2) ? histX : histZ;
      int t2 = t & 127;
      int wb = t2 * 8;
      unsigned run = 0;
#pragma unroll
      for (int c = 0; c < 8; ++c) {
        int w = hsw(wb + c);
        unsigned v = h[w];
        unsigned lo = v & 0xFFFFu;
        h[w] = run | ((run + lo) << 16);
        run += lo + (v >> 16);
      }
      unsigned incl = run;
#pragma unroll
      for (int d = 1; d < 64; d <<= 1) {
        unsigned o = (unsigned)__shfl_up((int)incl, d, 64);
        if (lane >= d) incl += o;
      }
      if (lane == 63) xch[16 + wv] = incl;
      __syncthreads();
      unsigned base = incl - run;
      if (wv & 1) base += xch[16 + (wv - 1)];
      unsigned add = base * 0x10001u;
#pragma unroll
      for (int c = 0; c < 8; ++c) h[hsw(wb + c)] += add;
    }
    __syncthreads();

#pragma unroll
    for (int c = 0; c < 16; ++c) {
      unsigned qxv = (xw[c >> 1] >> ((c & 1) * 16)) & 0xFFFFu;
      unsigned qzv = (zw[c >> 1] >> ((c & 1) * 16)) & 0xFFFFu;
      unsigned bx = (unsigned)(int)fminf(
          fmaxf(((float)(int)qxv - lox) * scx, 0.0f), (float)(NBIN - 1));
      unsigned bz = (unsigned)(int)fminf(
          fmaxf(((float)(int)qzv - loz) * scz, 0.0f), (float)(NBIN - 1));
      unsigned shx = (bx & 1) * 16, shz = (bz & 1) * 16;
      unsigned basex = (histX[hsw((int)(bx >> 1))] >> shx) & 0xFFFFu;
      unsigned basez = (histZ[hsw((int)(bz >> 1))] >> shz) & 0xFFFFu;
      int rx = (int)(basex + ((oxp[c >> 1] >> ((c & 1) * 16)) & 0xFFFFu));
      int rz = (int)(basez + ((ozp[c >> 1] >> ((c & 1) * 16)) & 0xFFFFu));
      int d = rx - rz;
      rsum += d < 0 ? -d : d;
    }
    __syncthreads();

    cxa = nxa;
    cxb = nxb;
    cza = nza;
    czb = nzb;
  }

  // block reduce + global atomics + last-block finalize
#pragma unroll
  for (int d = 32; d; d >>= 1) {
    rsum += __shfl_xor(rsum, d, 64);
    pd += __shfl_xor(pd, d, 64);
  }
  if (lane == 0) {
    xch[wv] = (unsigned)rsum;
    ((float*)xch)[8 + wv] = pd;
  }
  __syncthreads();
  if (t == 0) {
    unsigned long long rtot =
        (unsigned long long)xch[0] + xch[1] + xch[2] + xch[3];
    float ptot = ((float*)xch)[8] + ((float*)xch)[9] + ((float*)xch)[10] +
                 ((float*)xch)[11];
    atomicAdd(rank_acc, rtot);
    atomicAdd(pd_acc, (double)ptot);
    __threadfence();
    unsigned old = atomicAdd(&qstats[ST_DONE], 1u);
    if (old == (unsigned)gridDim.x - 1u) {
      unsigned long long rall = atomicAdd(rank_acc, 0ull);
      double pall = atomicAdd(pd_acc, 0.0);
      double inv = 1.0 / ((double)N * (double)N);
      double rank_loss = (double)rall * inv / 32.0;        // K = 32
      double pdv = pall * inv / (2048.0 * 2048.0);         // undo q scaling
      out[0] = (float)(rank_loss + 0.5 * pdv);
      out[1] = (float)rank_loss;
      out[2] = (float)pdv;
    }
  }
}

// ---------------- launch ----------------
extern "C" void kernel_launch(void* const* d_in, const int* in_sizes, int n_in,
                              void* d_out, int out_size, void* d_ws,
                              size_t ws_size, hipStream_t stream) {
  (void)in_sizes; (void)n_in; (void)out_size; (void)ws_size;
  const float* x = (const float*)d_in[0];
  const float* z = (const float*)d_in[1];
  float* out = (float*)d_out;

  char* w = (char*)d_ws;
  unsigned short* qx16 = (unsigned short*)(w);             // 32 MB
  unsigned short* qz16 = (unsigned short*)(w + 33554432);  // 32 MB
  __hip_bfloat16* xb = (__hip_bfloat16*)(w + 67108864);    // 4 MB
  __hip_bfloat16* zb = (__hip_bfloat16*)(w + 71303168);    // 0.5 MB
  float* nx = (float*)(w + 71827456);
  float* nz = (float*)(w + 71843840);
  unsigned* qstats = (unsigned*)(w + 71860224);

  prep_kernel<<<N / 4, 256, 0, stream>>>(x, z, xb, zb, nx, nz, qstats);

  gram_both_kernel<<<NTRI, 256, 0, stream>>>(xb, zb, nx, nz, qx16, qz16,
                                             qstats);

  rank_kernel<<<N / RPB, 256, 0, stream>>>(qx16, qz16, qstats, out);
}

// Round 16
// 168.206 us; speedup vs baseline: 1.2910x; 1.0347x over previous
//
#include <hip/hip_runtime.h>
#include <hip/hip_bf16.h>

// Problem: N=4096, Dx=512, Dz=64.
// out[0]=total, out[1]=rank_loss, out[2]=pairdist_loss (f32).
//
// Pipeline:
//   1. prep (barrier-free): one wave per row; float4 loads, shuffle-only
//      reductions, packed bf16 ushort4 stores; inits qstats.
//   2. gram_both: 528 symmetric triangular 128-tiles, each block does
//      z-tile (K=64) then x-tile (K=512). BK=64 PER BARRIER (two 32-col
//      sub-tiles per buffer, m97-verified LDS layout each) — halves the
//      K-loop barrier count vs r15 at UNCHANGED ~2 blocks/CU (64 KB LDS,
//      dbuf). r12-r14 established cost is per-barrier (~2000 cyc) not
//      per-byte/per-MFMA. LDS-staged coalesced uint4 dist writes; mirror
//      tile via LDS transpose restage. q0=min(floor(d*qscale),65535),
//      qscale 1024 (x) / 2048 (z). mmx aliased into smem (all uses are
//      barrier-separated from staging/ctile lifetimes) -> exactly 64 KB.
//   3. rank kernel: 1024 blocks x 256 thr, 4 rows/block, register
//      prefetch; global-normalized 11-bit bins; ds_add_rtn count+offset
//      pass; dual scan; plain ds_read final pass; |rx-rz| inline; last
//      block (done-counter) computes the 3 output scalars.

#define N 4096
#define DX 512
#define DZ 64
#define NBIN 2048
#define NWRD (NBIN / 2)
#define RPB 4

typedef __attribute__((ext_vector_type(8))) short short8;
typedef __attribute__((ext_vector_type(4))) float float4v;

// qstats word layout (u32 index):
//   [0..1] rank_acc (u64)  [2..3] pd_acc (double)
//   [4] maxx [5] maxz      [6] minx [7] minz    [8] done-counter
#define ST_MAX 4
#define ST_MIN 6
#define ST_DONE 8

// ---------------- async 16B global -> LDS ----------------
__device__ __forceinline__ void async16(const void* g, void* l) {
  __builtin_amdgcn_global_load_lds(
      (const __attribute__((address_space(1))) unsigned int*)(g),
      (__attribute__((address_space(3))) unsigned int*)(l), 16, 0, 0);
}

// ---------------- prep: barrier-free wave-per-row ----------------
__global__ __launch_bounds__(256) void prep_kernel(
    const float* __restrict__ x, const float* __restrict__ z,
    __hip_bfloat16* __restrict__ xb, __hip_bfloat16* __restrict__ zb,
    float* __restrict__ nx, float* __restrict__ nz,
    unsigned* __restrict__ qstats) {
  int tid = threadIdx.x;
  if (blockIdx.x == 0 && tid < 9)
    qstats[tid] = (tid == 6 || tid == 7) ? 0xFFFFFFFFu : 0u;

  int lane = tid & 63;
  int row = (int)blockIdx.x * 4 + (tid >> 6);

  const float4* xr = (const float4*)(x + (size_t)row * DX);
  float4 a = xr[lane];
  float4 b = xr[lane + 64];
  float s = a.x * a.x + a.y * a.y + a.z * a.z + a.w * a.w +
            b.x * b.x + b.y * b.y + b.z * b.z + b.w * b.w;
#pragma unroll
  for (int d = 32; d; d >>= 1) s += __shfl_xor(s, d, 64);
  if (lane == 0) nx[row] = s;

  ushort4 pa, pb;
  pa.x = __bfloat16_as_ushort(__float2bfloat16(a.x));
  pa.y = __bfloat16_as_ushort(__float2bfloat16(a.y));
  pa.z = __bfloat16_as_ushort(__float2bfloat16(a.z));
  pa.w = __bfloat16_as_ushort(__float2bfloat16(a.w));
  pb.x = __bfloat16_as_ushort(__float2bfloat16(b.x));
  pb.y = __bfloat16_as_ushort(__float2bfloat16(b.y));
  pb.z = __bfloat16_as_ushort(__float2bfloat16(b.z));
  pb.w = __bfloat16_as_ushort(__float2bfloat16(b.w));
  ushort4* xbo = (ushort4*)(xb + (size_t)row * DX);
  xbo[lane] = pa;
  xbo[lane + 64] = pb;

  float4 c = {0.f, 0.f, 0.f, 0.f};
  if (lane < 16) c = ((const float4*)(z + (size_t)row * DZ))[lane];
  float sz = c.x * c.x + c.y * c.y + c.z * c.z + c.w * c.w;
#pragma unroll
  for (int d = 32; d; d >>= 1) sz += __shfl_xor(sz, d, 64);
  if (lane == 0) nz[row] = sz;
  if (lane < 16) {
    ushort4 pc;
    pc.x = __bfloat16_as_ushort(__float2bfloat16(c.x));
    pc.y = __bfloat16_as_ushort(__float2bfloat16(c.y));
    pc.z = __bfloat16_as_ushort(__float2bfloat16(c.z));
    pc.w = __bfloat16_as_ushort(__float2bfloat16(c.w));
    ((ushort4*)(zb + (size_t)row * DZ))[lane] = pc;
  }
}

// ------- bf16 MFMA Gram, BK=64/barrier, symmetric triangular grid --------
#define TILE 128
#define BK 64     // staged K per barrier (two 32-col sub-tiles)
#define PADW 132  // ctile row stride in u16 (66 words, 8B-aligned b64)
#define NT 32
#define NTRI 528

// smem layout (65536 B total):
//   buffer b (b=0,1) at b*32768:
//     A-half0 @0, A-half1 @8192, B-half0 @16384, B-half1 @24576 (each 8 KB,
//     [128][32] bf16 — identical bank layout to the m97-verified BK=32 tile)
//   ctile aliases smem[0..33791] after the K-loop.
//   mmx aliases smem[0..31] in the final (barrier-separated) reduce phase.

__device__ __forceinline__ void gram_tile(
    const __hip_bfloat16* __restrict__ Abf, const float* __restrict__ norms,
    unsigned short* __restrict__ distq, int K, float qscale,
    unsigned* __restrict__ qstats, int slot, int by, int bx, char* smem) {
  unsigned short* ctile = (unsigned short*)smem;
  unsigned* mmx = (unsigned*)smem;

  int tid = threadIdx.x;
  int wave = tid >> 6, lane = tid & 63;
  int wr = wave >> 1, wc = wave & 1;
  int quad = lane >> 4, l15 = lane & 15;

  int rowBase = by * TILE;
  int colBase = bx * TILE;

  float4v acc[4][4];
#pragma unroll
  for (int mi = 0; mi < 4; ++mi)
#pragma unroll
    for (int ni = 0; ni < 4; ++ni) {
      float4v zv = {0.f, 0.f, 0.f, 0.f};
      acc[mi][ni] = zv;
    }

  const char* Ab = (const char*)Abf;
  const size_t rb = (size_t)K * 2;
  int chunk0 = wave * 2, chunk1 = wave * 2 + 1;
  int rl = lane >> 2;
  int cl = (lane & 3) * 16;

  // stage BK=64 chunk (two 32-col halves) into buffer b
  auto stage = [&](int kc, int b) {
#pragma unroll
    for (int h = 0; h < 2; ++h) {
      const char* base = Ab + (size_t)(kc + h * 32) * 2 + cl;
      short* sA = (short*)(smem + b * 32768 + h * 8192);
      short* sB = (short*)(smem + b * 32768 + 16384 + h * 8192);
      async16(base + (size_t)(rowBase + chunk0 * 16 + rl) * rb,
              &sA[chunk0 * 512]);
      async16(base + (size_t)(rowBase + chunk1 * 16 + rl) * rb,
              &sA[chunk1 * 512]);
      async16(base + (size_t)(colBase + chunk0 * 16 + rl) * rb,
              &sB[chunk0 * 512]);
      async16(base + (size_t)(colBase + chunk1 * 16 + rl) * rb,
              &sB[chunk1 * 512]);
    }
  };

  stage(0, 0);
  int ib = 0;
  for (int kc = 0; kc < K; kc += BK, ib ^= 1) {
    __syncthreads();  // drains current buf's staging; prev readers done
    if (kc + BK < K) stage(kc + BK, ib ^ 1);

#pragma unroll
    for (int h = 0; h < 2; ++h) {
      const short* As = (const short*)(smem + ib * 32768 + h * 8192);
      const short* Bs = (const short*)(smem + ib * 32768 + 16384 + h * 8192);
      short8 a[4], b[4];
#pragma unroll
      for (int mi = 0; mi < 4; ++mi)
        a[mi] =
            *(const short8*)(&As[(wr * 64 + mi * 16 + l15) * 32 + quad * 8]);
#pragma unroll
      for (int ni = 0; ni < 4; ++ni)
        b[ni] =
            *(const short8*)(&Bs[(wc * 64 + ni * 16 + l15) * 32 + quad * 8]);
#pragma unroll
      for (int mi = 0; mi < 4; ++mi)
#pragma unroll
        for (int ni = 0; ni < 4; ++ni)
          acc[mi][ni] = __builtin_amdgcn_mfma_f32_16x16x32_bf16(
              a[mi], b[ni], acc[mi][ni], 0, 0, 0);
    }
  }
  __syncthreads();  // all staging reads done before ctile aliasing write

  // quantize: stage [row][col] in LDS + keep packed u64 per column
  unsigned mn = 0xFFFFu, mx = 0u;
  unsigned long long qp[4][4];
#pragma unroll
  for (int mi = 0; mi < 4; ++mi) {
#pragma unroll
    for (int ni = 0; ni < 4; ++ni) {
      int colL = wc * 64 + ni * 16 + l15;
      float ncol = norms[colBase + colL];
      unsigned long long pk = 0ull;
#pragma unroll
      for (int r = 0; r < 4; ++r) {
        int rowL = wr * 64 + mi * 16 + quad * 4 + r;
        int row = rowBase + rowL;
        float sq = norms[row] + ncol - 2.0f * acc[mi][ni][r];
        float d = sq > 0.f ? sqrtf(sq) : 0.f;
        if (row == colBase + colL) d = 0.f;
        unsigned q = (unsigned)(d * qscale);
        q = q > 65535u ? 65535u : q;
        ctile[rowL * PADW + colL] = (unsigned short)q;
        pk |= (unsigned long long)q << (16 * r);
        mx = max(mx, q);
        mn = min(mn, (row == colBase + colL) ? 0xFFFFu : q);
      }
      qp[mi][ni] = pk;
    }
  }
  __syncthreads();

  // pass A: upper tile, coalesced uint4 rows
  {
    const unsigned* cw = (const unsigned*)ctile;
    int i0 = tid >> 4, k4 = (tid & 15) * 4;
#pragma unroll
    for (int s = 0; s < 8; ++s) {
      int i = s * 16 + i0;
      int wb = i * (PADW / 2) + k4;
      uint4 v;
      v.x = cw[wb + 0];
      v.y = cw[wb + 1];
      v.z = cw[wb + 2];
      v.w = cw[wb + 3];
      *(uint4*)(distq + (size_t)(rowBase + i) * N + colBase + (tid & 15) * 8) =
          v;
    }
  }

  // pass B: mirror tile via transposed restage (off-diag only)
  if (by != bx) {
    __syncthreads();
#pragma unroll
    for (int mi = 0; mi < 4; ++mi)
#pragma unroll
      for (int ni = 0; ni < 4; ++ni) {
        int colL = wc * 64 + ni * 16 + l15;
        int rowL0 = wr * 64 + mi * 16 + quad * 4;
        *(unsigned long long*)&ctile[colL * PADW + rowL0] = qp[mi][ni];
      }
    __syncthreads();
    const unsigned* cw = (const unsigned*)ctile;
    int j0 = tid >> 4, k4 = (tid & 15) * 4;
#pragma unroll
    for (int s = 0; s < 8; ++s) {
      int j = s * 16 + j0;
      int wb = j * (PADW / 2) + k4;
      uint4 v;
      v.x = cw[wb + 0];
      v.y = cw[wb + 1];
      v.z = cw[wb + 2];
      v.w = cw[wb + 3];
      *(uint4*)(distq + (size_t)(colBase + j) * N + rowBase + (tid & 15) * 8) =
          v;
    }
  }

  // block-level min/max reduce -> 2 device atomics per tile
#pragma unroll
  for (int d = 32; d; d >>= 1) {
    mn = min(mn, (unsigned)__shfl_xor((int)mn, d, 64));
    mx = max(mx, (unsigned)__shfl_xor((int)mx, d, 64));
  }
  __syncthreads();  // ctile/pass-B reads done; mmx aliasing safe
  if (lane == 0) {
    mmx[wave] = mn;
    mmx[4 + wave] = mx;
  }
  __syncthreads();
  if (tid == 0) {
    unsigned bmn = min(min(mmx[0], mmx[1]), min(mmx[2], mmx[3]));
    unsigned bmx = max(max(mmx[4], mmx[5]), max(mmx[6], mmx[7]));
    atomicMin(&qstats[ST_MIN + slot], bmn);
    atomicMax(&qstats[ST_MAX + slot], bmx);
  }
}

__global__ __launch_bounds__(256) void gram_both_kernel(
    const __hip_bfloat16* __restrict__ xb, const __hip_bfloat16* __restrict__ zb,
    const float* __restrict__ nx, const float* __restrict__ nz,
    unsigned short* __restrict__ qx16, unsigned short* __restrict__ qz16,
    unsigned* __restrict__ qstats) {
  __shared__ alignas(16) char smem[65536];  // dbuf staging; ctile/mmx aliased

  // compact upper-triangular decode: row-major rows by=0..31, len 32-by
  int idx = (int)blockIdx.x;
  int by = (int)((65.0f - sqrtf(4225.0f - 8.0f * (float)idx)) * 0.5f);
  while (((by + 1) * (65 - (by + 1))) / 2 <= idx) ++by;
  while ((by * (65 - by)) / 2 > idx) --by;
  int bx = by + (idx - (by * (65 - by)) / 2);

  gram_tile(zb, nz, qz16, DZ, 2048.0f, qstats, 1, by, bx, smem);
  __syncthreads();
  gram_tile(xb, nx, qx16, DX, 1024.0f, qstats, 0, by, bx, smem);
}

// ---------------- counting-based per-row ranks (4 rows / block) ----------
__device__ __forceinline__ int hsw(int w) { return w ^ ((w >> 5) & 31); }

__global__ __launch_bounds__(256) void rank_kernel(
    const unsigned short* __restrict__ qx,
    const unsigned short* __restrict__ qz, unsigned* __restrict__ qstats,
    float* __restrict__ out) {
  __shared__ unsigned histX[NWRD];
  __shared__ unsigned histZ[NWRD];
  __shared__ unsigned xch[32];

  unsigned long long* rank_acc = (unsigned long long*)qstats;
  double* pd_acc = (double*)(qstats + 2);

  int t = threadIdx.x, lane = t & 63, wv = t >> 6;
  int row0 = (int)blockIdx.x * RPB;

  float lox = (float)(int)qstats[ST_MIN + 0];
  float scx = (float)(NBIN - 1) /
              (float)(int)max(1u, qstats[ST_MAX + 0] - qstats[ST_MIN + 0]);
  float loz = (float)(int)qstats[ST_MIN + 1];
  float scz = (float)(NBIN - 1) /
              (float)(int)max(1u, qstats[ST_MAX + 1] - qstats[ST_MIN + 1]);

  const uint4* px = (const uint4*)(qx + (size_t)row0 * N);
  const uint4* pz = (const uint4*)(qz + (size_t)row0 * N);

  uint4 cxa = px[t * 2], cxb = px[t * 2 + 1];
  uint4 cza = pz[t * 2], czb = pz[t * 2 + 1];

  float pd = 0.f;
  int rsum = 0;

#pragma unroll 1
  for (int r = 0; r < RPB; ++r) {
#pragma unroll
    for (int i = 0; i < 4; ++i) {
      histX[t + 256 * i] = 0u;
      histZ[t + 256 * i] = 0u;
    }
    uint4 nxa = cxa, nxb = cxb, nza = cza, nzb = czb;
    if (r + 1 < RPB) {
      const uint4* npx = px + (size_t)(r + 1) * (N / 8);
      const uint4* npz = pz + (size_t)(r + 1) * (N / 8);
      nxa = npx[t * 2];
      nxb = npx[t * 2 + 1];
      nza = npz[t * 2];
      nzb = npz[t * 2 + 1];
    }

    unsigned xw[8] = {cxa.x, cxa.y, cxa.z, cxa.w, cxb.x, cxb.y, cxb.z, cxb.w};
    unsigned zw[8] = {cza.x, cza.y, cza.z, cza.w, czb.x, czb.y, czb.z, czb.w};

#pragma unroll
    for (int c = 0; c < 16; ++c) {
      unsigned qxv = (xw[c >> 1] >> ((c & 1) * 16)) & 0xFFFFu;
      unsigned qzv = (zw[c >> 1] >> ((c & 1) * 16)) & 0xFFFFu;
      // dz-dx = (qz - 2*qx - 0.5)/2048
      float tv = (float)(int)qzv - 2.0f * (float)(int)qxv - 0.5f;
      pd += tv * tv;
    }
    __syncthreads();

    unsigned oxp[8], ozp[8];
#pragma unroll
    for (int c = 0; c < 16; ++c) {
      unsigned qxv = (xw[c >> 1] >> ((c & 1) * 16)) & 0xFFFFu;
      unsigned qzv = (zw[c >> 1] >> ((c & 1) * 16)) & 0xFFFFu;
      unsigned bx = (unsigned)(int)fminf(
          fmaxf(((float)(int)qxv - lox) * scx, 0.0f), (float)(NBIN - 1));
      unsigned bz = (unsigned)(int)fminf(
          fmaxf(((float)(int)qzv - loz) * scz, 0.0f), (float)(NBIN - 1));
      unsigned shx = (bx & 1) * 16, shz = (bz & 1) * 16;
      unsigned ox =
          (atomicAdd(&histX[hsw((int)(bx >> 1))], 1u << shx) >> shx) & 0xFFFFu;
      unsigned oz =
          (atomicAdd(&histZ[hsw((int)(bz >> 1))], 1u << shz) >> shz) & 0xFFFFu;
      if (c & 1) {
        oxp[c >> 1] |= ox << 16;
        ozp[c >> 1] |= oz << 16;
      } else {
        oxp[c >> 1] = ox;
        ozp[c >> 1] = oz;
      }
    }
    __syncthreads();

    {
      unsigned* h = (wv < 2) ? histX : histZ;
      int t2 = t & 127;
      int wb = t2 * 8;
      unsigned run = 0;
#pragma unroll
      for (int c = 0; c < 8; ++c) {
        int w = hsw(wb + c);
        unsigned v = h[w];
        unsigned lo = v & 0xFFFFu;
        h[w] = run | ((run + lo) << 16);
        run += lo + (v >> 16);
      }
      unsigned incl = run;
#pragma unroll
      for (int d = 1; d < 64; d <<= 1) {
        unsigned o = (unsigned)__shfl_up((int)incl, d, 64);
        if (lane >= d) incl += o;
      }
      if (lane == 63) xch[16 + wv] = incl;
      __syncthreads();
      unsigned base = incl - run;
      if (wv & 1) base += xch[16 + (wv - 1)];
      unsigned add = base * 0x10001u;
#pragma unroll
      for (int c = 0; c < 8; ++c) h[hsw(wb + c)] += add;
    }
    __syncthreads();

#pragma unroll
    for (int c = 0; c < 16; ++c) {
      unsigned qxv = (xw[c >> 1] >> ((c & 1) * 16)) & 0xFFFFu;
      unsigned qzv = (zw[c >> 1] >> ((c & 1) * 16)) & 0xFFFFu;
      unsigned bx = (unsigned)(int)fminf(
          fmaxf(((float)(int)qxv - lox) * scx, 0.0f), (float)(NBIN - 1));
      unsigned bz = (unsigned)(int)fminf(
          fmaxf(((float)(int)qzv - loz) * scz, 0.0f), (float)(NBIN - 1));
      unsigned shx = (bx & 1) * 16, shz = (bz & 1) * 16;
      unsigned basex = (histX[hsw((int)(bx >> 1))] >> shx) & 0xFFFFu;
      unsigned basez = (histZ[hsw((int)(bz >> 1))] >> shz) & 0xFFFFu;
      int rx = (int)(basex + ((oxp[c >> 1] >> ((c & 1) * 16)) & 0xFFFFu));
      int rz = (int)(basez + ((ozp[c >> 1] >> ((c & 1) * 16)) & 0xFFFFu));
      int d = rx - rz;
      rsum += d < 0 ? -d : d;
    }
    __syncthreads();

    cxa = nxa;
    cxb = nxb;
    cza = nza;
    czb = nzb;
  }

  // block reduce + global atomics + last-block finalize
#pragma unroll
  for (int d = 32; d; d >>= 1) {
    rsum += __shfl_xor(rsum, d, 64);
    pd += __shfl_xor(pd, d, 64);
  }
  if (lane == 0) {
    xch[wv] = (unsigned)rsum;
    ((float*)xch)[8 + wv] = pd;
  }
  __syncthreads();
  if (t == 0) {
    unsigned long long rtot =
        (unsigned long long)xch[0] + xch[1] + xch[2] + xch[3];
    float ptot = ((float*)xch)[8] + ((float*)xch)[9] + ((float*)xch)[10] +
                 ((float*)xch)[11];
    atomicAdd(rank_acc, rtot);
    atomicAdd(pd_acc, (double)ptot);
    __threadfence();
    unsigned old = atomicAdd(&qstats[ST_DONE], 1u);
    if (old == (unsigned)gridDim.x - 1u) {
      unsigned long long rall = atomicAdd(rank_acc, 0ull);
      double pall = atomicAdd(pd_acc, 0.0);
      double inv = 1.0 / ((double)N * (double)N);
      double rank_loss = (double)rall * inv / 32.0;  // K = 32
      double pdv = pall * inv / (2048.0 * 2048.0);   // undo q scaling
      out[0] = (float)(rank_loss + 0.5 * pdv);
      out[1] = (float)rank_loss;
      out[2] = (float)pdv;
    }
  }
}

// ---------------- launch ----------------
extern "C" void kernel_launch(void* const* d_in, const int* in_sizes, int n_in,
                              void* d_out, int out_size, void* d_ws,
                              size_t ws_size, hipStream_t stream) {
  (void)in_sizes; (void)n_in; (void)out_size; (void)ws_size;
  const float* x = (const float*)d_in[0];
  const float* z = (const float*)d_in[1];
  float* out = (float*)d_out;

  char* w = (char*)d_ws;
  unsigned short* qx16 = (unsigned short*)(w);             // 32 MB
  unsigned short* qz16 = (unsigned short*)(w + 33554432);  // 32 MB
  __hip_bfloat16* xb = (__hip_bfloat16*)(w + 67108864);    // 4 MB
  __hip_bfloat16* zb = (__hip_bfloat16*)(w + 71303168);    // 0.5 MB
  float* nx = (float*)(w + 71827456);
  float* nz = (float*)(w + 71843840);
  unsigned* qstats = (unsigned*)(w + 71860224);

  prep_kernel<<<N / 4, 256, 0, stream>>>(x, z, xb, zb, nx, nz, qstats);

  gram_both_kernel<<<NTRI, 256, 0, stream>>>(xb, zb, nx, nz, qx16, qz16,
                                             qstats);

  rank_kernel<<<N / RPB, 256, 0, stream>>>(qx16, qz16, qstats, out);
}